// Round 3
// baseline (707.455 us; speedup 1.0000x reference)
//
#include <hip/hip_runtime.h>
#include <math.h>

#define NH 512
#define BATCH 256
#define TT 512
#define NSTEPS 511           // recurrence steps (t = 0..510 produce states 1..511)
#define ALPHA 0.2f
#define OMA 0.8f
// sqrt(2/0.2 * 0.2^2) = sqrt(0.4)
#define ISCALE 0.6324555320336759f
#define PD 12                // noise prefetch depth (steps in flight per wave)
#define WPB 8                // waves per batch block: each wave owns 64 hidden units

typedef float vf2 __attribute__((ext_vector_type(2)));

// ---------------- helpers ----------------

__device__ __forceinline__ float wave_reduce_sum(float v) {
#pragma unroll
    for (int m = 32; m >= 1; m >>= 1) v += __shfl_xor(v, m, 64);
    return v;
}

__device__ __forceinline__ unsigned long long enc_key(float v, int i) {
    // v >= 0: float bits are order-preserving
    return (((unsigned long long)__float_as_uint(v)) << 32) | (unsigned int)i;
}

__device__ __forceinline__ unsigned long long wave_max_key(unsigned long long k) {
#pragma unroll
    for (int m = 32; m >= 1; m >>= 1) {
        unsigned long long o = __shfl_xor(k, m, 64);
        k = (o > k) ? o : k;
    }
    return k;
}

// argmax index over rn[0..511], computed redundantly per wave (deterministic).
// lane must be 0..63.
__device__ __forceinline__ int scan_argmax_rn(const float* __restrict__ rn, int lane) {
    const float4* rn4 = (const float4*)rn;
    unsigned long long key = 0;
#pragma unroll
    for (int r = 0; r < 2; ++r) {
        float4 v = rn4[lane + 64 * r];
        int base = 4 * (lane + 64 * r);
        unsigned long long k0 = enc_key(v.x, base);
        unsigned long long k1 = enc_key(v.y, base + 1);
        unsigned long long k2 = enc_key(v.z, base + 2);
        unsigned long long k3 = enc_key(v.w, base + 3);
        k0 = k0 > k1 ? k0 : k1;
        k2 = k2 > k3 ? k2 : k3;
        k0 = k0 > k2 ? k0 : k2;
        key = key > k0 ? key : k0;
    }
    return (int)(wave_max_key(key) & 0xffffffffULL);
}

// full-wave sum via DPP (VALU pipe, no LDS): result valid in lane 63
__device__ __forceinline__ float dpp_sum63(float v) {
    v += __int_as_float(__builtin_amdgcn_update_dpp(0, __float_as_int(v), 0x111, 0xf, 0xf, true)); // row_shr:1
    v += __int_as_float(__builtin_amdgcn_update_dpp(0, __float_as_int(v), 0x112, 0xf, 0xf, true)); // row_shr:2
    v += __int_as_float(__builtin_amdgcn_update_dpp(0, __float_as_int(v), 0x114, 0xf, 0xf, true)); // row_shr:4
    v += __int_as_float(__builtin_amdgcn_update_dpp(0, __float_as_int(v), 0x118, 0xf, 0xf, true)); // row_shr:8
    v += __int_as_float(__builtin_amdgcn_update_dpp(0, __float_as_int(v), 0x142, 0xa, 0xf, true)); // row_bcast15
    v += __int_as_float(__builtin_amdgcn_update_dpp(0, __float_as_int(v), 0x143, 0xc, 0xf, true)); // row_bcast31
    return v;
}

// ---------------- fused setup: rank-2 factorization of W_rec ----------------
// Single block, 4 waves. Identical math + reduction orders to the previous
// 3-kernel version (k_rownorm/k_rowdot/k_computeP) => bitwise-same P/idx.
// ws layout: idx @0 (2 ints), P @64 (1024 f)

__global__ __launch_bounds__(256, 1)
void k_setup(const float* __restrict__ W, float* __restrict__ P, int* __restrict__ idx) {
    __shared__ __align__(16) float rn_s[NH];
    __shared__ __align__(16) float dv_s[NH];
    const int tid = threadIdx.x, wid = tid >> 6, lane = tid & 63;

    // phase 1: row norms rn[i] = ||W[i,:]||^2
    for (int row = wid; row < NH; row += 4) {
        const float4* r4 = (const float4*)(W + (size_t)row * NH);
        float acc = 0.f;
#pragma unroll
        for (int r = 0; r < 2; ++r) {
            float4 v = r4[lane + 64 * r];
            acc = fmaf(v.x, v.x, fmaf(v.y, v.y, fmaf(v.z, v.z, fmaf(v.w, v.w, acc))));
        }
        acc = wave_reduce_sum(acc);
        if (lane == 0) rn_s[row] = acc;
    }
    __syncthreads();

    const int i1 = scan_argmax_rn(rn_s, lane);   // per-wave redundant, deterministic
    const float rn1 = rn_s[i1];
    const float inv1 = 1.f / rn1;

    // cache row i1 in registers
    const float4* row1 = (const float4*)(W + (size_t)i1 * NH);
    const float4 b0 = row1[lane], b1 = row1[lane + 64];

    // phase 2: dv[i] = <W[i,:], W[i1,:]>
    for (int row = wid; row < NH; row += 4) {
        const float4* r4 = (const float4*)(W + (size_t)row * NH);
        float acc = 0.f;
        {
            float4 a = r4[lane];
            acc = fmaf(a.x, b0.x, fmaf(a.y, b0.y, fmaf(a.z, b0.z, fmaf(a.w, b0.w, acc))));
            a = r4[lane + 64];
            acc = fmaf(a.x, b1.x, fmaf(a.y, b1.y, fmaf(a.z, b1.z, fmaf(a.w, b1.w, acc))));
        }
        acc = wave_reduce_sum(acc);
        if (lane == 0) dv_s[row] = acc;
    }
    __syncthreads();

    // phase 3: residual argmax -> i2 (exclude i1); redundant per wave
    const float4* rn4 = (const float4*)rn_s;
    const float4* dv4 = (const float4*)dv_s;
    unsigned long long key = 0;
#pragma unroll
    for (int r = 0; r < 2; ++r) {
        float4 a = rn4[lane + 64 * r];
        float4 d = dv4[lane + 64 * r];
        int base = 4 * (lane + 64 * r);
        float r0 = fmaxf(a.x - d.x * d.x * inv1, 0.f);
        float r1 = fmaxf(a.y - d.y * d.y * inv1, 0.f);
        float r2 = fmaxf(a.z - d.z * d.z * inv1, 0.f);
        float r3 = fmaxf(a.w - d.w * d.w * inv1, 0.f);
        unsigned long long k0 = (base + 0 != i1) ? enc_key(r0, base + 0) : 0ULL;
        unsigned long long k1 = (base + 1 != i1) ? enc_key(r1, base + 1) : 0ULL;
        unsigned long long k2 = (base + 2 != i1) ? enc_key(r2, base + 2) : 0ULL;
        unsigned long long k3 = (base + 3 != i1) ? enc_key(r3, base + 3) : 0ULL;
        k0 = k0 > k1 ? k0 : k1;
        k2 = k2 > k3 ? k2 : k3;
        k0 = k0 > k2 ? k0 : k2;
        key = key > k0 ? key : k0;
    }
    const int i2 = (int)(wave_max_key(key) & 0xffffffffULL);

    // phase 4: least-squares P[n,0:2] (pre-scaled by ALPHA)
    const float4* row2 = (const float4*)(W + (size_t)i2 * NH);
    const float4 c0 = row2[lane], c1 = row2[lane + 64];
    const float g11 = rn1, g22 = rn_s[i2], g12 = dv_s[i2];
    const float det = fmaf(g11, g22, -g12 * g12);
    const float invd = 1.f / det;
    for (int row = wid; row < NH; row += 4) {
        const float4* r4 = (const float4*)(W + (size_t)row * NH);
        float t0 = 0.f, t1 = 0.f;
        {
            float4 a = r4[lane];
            t0 = fmaf(a.x, b0.x, fmaf(a.y, b0.y, fmaf(a.z, b0.z, fmaf(a.w, b0.w, t0))));
            t1 = fmaf(a.x, c0.x, fmaf(a.y, c0.y, fmaf(a.z, c0.z, fmaf(a.w, c0.w, t1))));
            a = r4[lane + 64];
            t0 = fmaf(a.x, b1.x, fmaf(a.y, b1.y, fmaf(a.z, b1.z, fmaf(a.w, b1.w, t0))));
            t1 = fmaf(a.x, c1.x, fmaf(a.y, c1.y, fmaf(a.z, c1.z, fmaf(a.w, c1.w, t1))));
        }
        t0 = wave_reduce_sum(t0);
        t1 = wave_reduce_sum(t1);
        if (lane == 0) {
            P[2 * row]     = ALPHA * ((g22 * t0 - g12 * t1) * invd);
            P[2 * row + 1] = ALPHA * ((g11 * t1 - g12 * t0) * invd);
        }
    }
    if (tid == 0) { idx[0] = i1; idx[1] = i2; }
}

// ---------------- main recurrence ----------------
// 8 waves per batch (block = 512 threads); each wave owns 64 hidden units,
// each lane 1. Rank-2 coupling: waves exchange only 2 scalar partials per
// step via a 64 B double-buffered LDS slot + ONE barrier/step.
//
// Barrier-ordering safety (single barrier, 2 buffers): wave w's write(t+2)
// into slot t&1 happens only after w passed bar(t+1); every wave passes
// bar(t+1) only after its read(t). So no write can pass an unread value.
//
// Why 8 waves: streaming BW per wave saturates (~5 B/cyc); m13 shows peak
// HBM needs ~8 waves/CU. Per-CU traffic is 4 KB/step (2 KB rnoise read +
// 2 KB out write) -> 400 cyc/step floor at 6.3 TB/s; the serial chain
// (fmax->mul->6 DPP->LDS xchg->bar->4 b128 bcast reads->tree->2 FMA) is
// ~280 cyc, so memory stays the binding constraint.
__launch_bounds__(512, 1)
__global__ void k_main(const float* __restrict__ u, const float* __restrict__ inoise,
                       const float* __restrict__ rnoise, const float* __restrict__ W_in,
                       const float* __restrict__ W, const float* __restrict__ b_rec,
                       const int* __restrict__ idx, const float* __restrict__ P,
                       float* __restrict__ out) {
    __shared__ __align__(16) float2 lds_x[TT];      // x[t,0:2] = u + ISCALE*input_noise
    __shared__ __align__(16) float2 lds_p[2][WPB];  // per-wave (p0,p1) partials, dbuf
    const int b = blockIdx.x;
    const int tid = threadIdx.x;        // 0..511
    const int wid = tid >> 6;
    const int lane = tid & 63;
    const int i1 = idx[0];
    const int i2 = idx[1];

    // stage x: 1024 floats = 512 float2, one per thread
    {
        const float2* u2 = (const float2*)(u + (size_t)b * TT * 2);
        const float2* n2 = (const float2*)(inoise + (size_t)b * TT * 2);
        float2 a = u2[tid];
        float2 c = n2[tid];
        float2 x;
        x.x = fmaf(ISCALE, c.x, a.x);
        x.y = fmaf(ISCALE, c.y, a.y);
        lds_x[tid] = x;
    }
    __syncthreads();

    // this lane's hidden unit
    const int n0 = (wid << 6) + lane;   // 0..511
    const float q0 = W[(size_t)i1 * NH + n0];
    const float q1 = W[(size_t)i2 * NH + n0];
    const float A0 = P[2 * n0];
    const float A1 = P[2 * n0 + 1];
    const float w0 = ALPHA * W_in[2 * n0];
    const float w1 = ALPHA * W_in[2 * n0 + 1];
    const float cb = ALPHA * b_rec[n0];
    float s = 0.f;

    const float* nzb = rnoise + (size_t)b * TT * NH + n0;
    float* ob = out + (size_t)b * TT * NH + n0;

    // states[:,0,:] = 0
    __builtin_nontemporal_store(0.f, ob);

    // noise prefetch: PD steps in flight, 4 B/lane each (coalesced 256 B/wave)
    float buf[PD];
#pragma unroll
    for (int k = 0; k < PD; ++k) buf[k] = __builtin_nontemporal_load(nzb + (size_t)k * NH);

#define STEP(t_, k_, REFILL_, XX_, XY_)                                              \
    {                                                                                \
        const int t = (t_);                                                          \
        float nz = buf[k_];                                                          \
        if (REFILL_) {                                                               \
            int tp = t + PD; if (tp > NSTEPS) tp = NSTEPS; /* row 511 is valid */    \
            buf[k_] = __builtin_nontemporal_load(nzb + (size_t)tp * NH);             \
        }                                                                            \
        const float xx = (XX_);                                                      \
        const float xy = (XY_);                                                      \
        float rs = fmaxf(s, 0.f);                                                    \
        float pa = rs * q0;                                                          \
        float pb = rs * q1;                                                          \
        pa = dpp_sum63(pa);                                                          \
        pb = dpp_sum63(pb);                                                          \
        /* base terms are off the p-chain: computed under barrier/LDS latency */     \
        float base = fmaf(ALPHA, nz, cb);                                            \
        base = fmaf(w0, xx, base);                                                   \
        base = fmaf(w1, xy, base);                                                   \
        base = fmaf(OMA, s, base);                                                   \
        if (lane == 63) lds_p[(t) & 1][wid] = make_float2(pa, pb);                   \
        __syncthreads();                                                             \
        const float4* pp = (const float4*)lds_p[(t) & 1];                            \
        float4 r0 = pp[0];                                                           \
        float4 r1 = pp[1];                                                           \
        float4 r2 = pp[2];                                                           \
        float4 r3 = pp[3];                                                           \
        float p0 = ((r0.x + r0.z) + (r1.x + r1.z)) + ((r2.x + r2.z) + (r3.x + r3.z));\
        float p1 = ((r0.y + r0.w) + (r1.y + r1.w)) + ((r2.y + r2.w) + (r3.y + r3.w));\
        s = fmaf(A1, p1, fmaf(A0, p0, base));                                        \
        __builtin_nontemporal_store(s, ob + (size_t)(t + 1) * NH);                   \
    }

    // 511 = 42*12 + 7: full blocks cover t in [0,504), tail covers [504,511)
    for (int tb = 0; tb < 504; tb += PD) {
        // hoist this block's 12 wave-uniform x reads (6 x ds_read_b128 broadcast)
        const float4* lxs = (const float4*)(lds_x + tb);
        float4 xb[6];
#pragma unroll
        for (int r = 0; r < 6; ++r) xb[r] = lxs[r];
#pragma unroll
        for (int k = 0; k < PD; ++k) {
            STEP(tb + k, k, true,
                 ((k & 1) ? xb[k >> 1].z : xb[k >> 1].x),
                 ((k & 1) ? xb[k >> 1].w : xb[k >> 1].y))
        }
    }
    {
        const float4* lxs = (const float4*)(lds_x + 504);
        float4 xb[4];
#pragma unroll
        for (int r = 0; r < 4; ++r) xb[r] = lxs[r];
#pragma unroll
        for (int k = 0; k < 7; ++k) {
            STEP(504 + k, k, false,
                 ((k & 1) ? xb[k >> 1].z : xb[k >> 1].x),
                 ((k & 1) ? xb[k >> 1].w : xb[k >> 1].y))
        }
    }

#undef STEP
}

// ---------------- launch ----------------

extern "C" void kernel_launch(void* const* d_in, const int* in_sizes, int n_in,
                              void* d_out, int out_size, void* d_ws, size_t ws_size,
                              hipStream_t stream) {
    const float* u      = (const float*)d_in[0];
    const float* inoise = (const float*)d_in[1];
    const float* rnoise = (const float*)d_in[2];
    const float* W_in   = (const float*)d_in[3];
    const float* W      = (const float*)d_in[4];
    const float* b_rec  = (const float*)d_in[5];
    float* out = (float*)d_out;

    char* ws = (char*)d_ws;
    int* idx  = (int*)(ws + 0);
    float* P  = (float*)(ws + 64);

    hipLaunchKernelGGL(k_setup, dim3(1), dim3(256), 0, stream, W, P, idx);
    hipLaunchKernelGGL(k_main, dim3(BATCH), dim3(512), 0, stream,
                       u, inoise, rnoise, W_in, W, b_rec, idx, P, out);
}

// Round 5
// 522.953 us; speedup vs baseline: 1.3528x; 1.3528x over previous
//
#include <hip/hip_runtime.h>
#include <math.h>

#define NH 512
#define BATCH 256
#define TT 512
#define NSTEPS 511           // recurrence steps (t = 0..510 produce states 1..511)
#define ALPHA 0.2f
#define OMA 0.8f
// sqrt(2/0.2 * 0.2^2) = sqrt(0.4)
#define ISCALE 0.6324555320336759f
#define PD 12                // noise prefetch depth (steps in flight per wave)
#define WPB 8                // waves per batch block: each wave owns 64 hidden units

typedef float vf2 __attribute__((ext_vector_type(2)));

// ---------------- helpers ----------------

__device__ __forceinline__ float wave_reduce_sum(float v) {
#pragma unroll
    for (int m = 32; m >= 1; m >>= 1) v += __shfl_xor(v, m, 64);
    return v;
}

__device__ __forceinline__ unsigned long long enc_key(float v, int i) {
    // v >= 0: float bits are order-preserving
    return (((unsigned long long)__float_as_uint(v)) << 32) | (unsigned int)i;
}

__device__ __forceinline__ unsigned long long wave_max_key(unsigned long long k) {
#pragma unroll
    for (int m = 32; m >= 1; m >>= 1) {
        unsigned long long o = __shfl_xor(k, m, 64);
        k = (o > k) ? o : k;
    }
    return k;
}

// argmax index over rn[0..511], computed redundantly per wave (deterministic)
__device__ __forceinline__ int scan_argmax_rn(const float* __restrict__ rn, int tid) {
    const float4* rn4 = (const float4*)rn;
    unsigned long long key = 0;
#pragma unroll
    for (int r = 0; r < 2; ++r) {
        float4 v = rn4[tid + 64 * r];
        int base = 4 * (tid + 64 * r);
        unsigned long long k0 = enc_key(v.x, base);
        unsigned long long k1 = enc_key(v.y, base + 1);
        unsigned long long k2 = enc_key(v.z, base + 2);
        unsigned long long k3 = enc_key(v.w, base + 3);
        k0 = k0 > k1 ? k0 : k1;
        k2 = k2 > k3 ? k2 : k3;
        k0 = k0 > k2 ? k0 : k2;
        key = key > k0 ? key : k0;
    }
    return (int)(wave_max_key(key) & 0xffffffffULL);
}

// full-wave sum via DPP (VALU pipe, no LDS): result valid in lane 63
__device__ __forceinline__ float dpp_sum63(float v) {
    v += __int_as_float(__builtin_amdgcn_update_dpp(0, __float_as_int(v), 0x111, 0xf, 0xf, true)); // row_shr:1
    v += __int_as_float(__builtin_amdgcn_update_dpp(0, __float_as_int(v), 0x112, 0xf, 0xf, true)); // row_shr:2
    v += __int_as_float(__builtin_amdgcn_update_dpp(0, __float_as_int(v), 0x114, 0xf, 0xf, true)); // row_shr:4
    v += __int_as_float(__builtin_amdgcn_update_dpp(0, __float_as_int(v), 0x118, 0xf, 0xf, true)); // row_shr:8
    v += __int_as_float(__builtin_amdgcn_update_dpp(0, __float_as_int(v), 0x142, 0xa, 0xf, true)); // row_bcast15
    v += __int_as_float(__builtin_amdgcn_update_dpp(0, __float_as_int(v), 0x143, 0xc, 0xf, true)); // row_bcast31
    return v;
}

// ---------------- setup: rank-2 factorization of W_rec ----------------
// Proven 3-kernel multi-block form (512 blocks each, ~10-20 us total).
// ws layout: idx @0 (2 ints), rn @64 (512 f), dv @2112 (512 f), P @4160 (1024 f)

__global__ void k_rownorm(const float* __restrict__ W, float* __restrict__ rn) {
    const int i = blockIdx.x, tid = threadIdx.x;
    const float4* row = (const float4*)(W + (size_t)i * NH);
    float acc = 0.f;
#pragma unroll
    for (int r = 0; r < 2; ++r) {
        float4 v = row[tid + 64 * r];
        acc = fmaf(v.x, v.x, fmaf(v.y, v.y, fmaf(v.z, v.z, fmaf(v.w, v.w, acc))));
    }
    acc = wave_reduce_sum(acc);
    if (tid == 0) rn[i] = acc;
}

__global__ void k_rowdot(const float* __restrict__ W, const float* __restrict__ rn,
                         float* __restrict__ dv) {
    const int i = blockIdx.x, tid = threadIdx.x;
    const int i1 = scan_argmax_rn(rn, tid);
    const float4* rowi = (const float4*)(W + (size_t)i * NH);
    const float4* row1 = (const float4*)(W + (size_t)i1 * NH);
    float acc = 0.f;
#pragma unroll
    for (int r = 0; r < 2; ++r) {
        float4 a = rowi[tid + 64 * r];
        float4 b = row1[tid + 64 * r];
        acc = fmaf(a.x, b.x, fmaf(a.y, b.y, fmaf(a.z, b.z, fmaf(a.w, b.w, acc))));
    }
    acc = wave_reduce_sum(acc);
    if (tid == 0) dv[i] = acc;
}

// Least-squares P[n,0:2] (pre-scaled by ALPHA): W[n,:] ~= c0*W[i1,:] + c1*W[i2,:]
__global__ void k_computeP(const float* __restrict__ W, const float* __restrict__ rn,
                           const float* __restrict__ dv, float* __restrict__ P,
                           int* __restrict__ idx) {
    const int n = blockIdx.x, tid = threadIdx.x;
    const int i1 = scan_argmax_rn(rn, tid);
    const float rn1 = rn[i1];
    const float inv1 = 1.f / rn1;

    // residual argmax -> i2 (exclude i1)
    const float4* rn4 = (const float4*)rn;
    const float4* dv4 = (const float4*)dv;
    unsigned long long key = 0;
#pragma unroll
    for (int r = 0; r < 2; ++r) {
        float4 a = rn4[tid + 64 * r];
        float4 d = dv4[tid + 64 * r];
        int base = 4 * (tid + 64 * r);
        float r0 = fmaxf(a.x - d.x * d.x * inv1, 0.f);
        float r1 = fmaxf(a.y - d.y * d.y * inv1, 0.f);
        float r2 = fmaxf(a.z - d.z * d.z * inv1, 0.f);
        float r3 = fmaxf(a.w - d.w * d.w * inv1, 0.f);
        unsigned long long k0 = (base + 0 != i1) ? enc_key(r0, base + 0) : 0ULL;
        unsigned long long k1 = (base + 1 != i1) ? enc_key(r1, base + 1) : 0ULL;
        unsigned long long k2 = (base + 2 != i1) ? enc_key(r2, base + 2) : 0ULL;
        unsigned long long k3 = (base + 3 != i1) ? enc_key(r3, base + 3) : 0ULL;
        k0 = k0 > k1 ? k0 : k1;
        k2 = k2 > k3 ? k2 : k3;
        k0 = k0 > k2 ? k0 : k2;
        key = key > k0 ? key : k0;
    }
    const int i2 = (int)(wave_max_key(key) & 0xffffffffULL);

    const float4* rown = (const float4*)(W + (size_t)n * NH);
    const float4* row1 = (const float4*)(W + (size_t)i1 * NH);
    const float4* row2 = (const float4*)(W + (size_t)i2 * NH);
    float t0 = 0.f, t1 = 0.f;
#pragma unroll
    for (int r = 0; r < 2; ++r) {
        float4 a = rown[tid + 64 * r];
        float4 b = row1[tid + 64 * r];
        float4 c = row2[tid + 64 * r];
        t0 = fmaf(a.x, b.x, fmaf(a.y, b.y, fmaf(a.z, b.z, fmaf(a.w, b.w, t0))));
        t1 = fmaf(a.x, c.x, fmaf(a.y, c.y, fmaf(a.z, c.z, fmaf(a.w, c.w, t1))));
    }
    t0 = wave_reduce_sum(t0);
    t1 = wave_reduce_sum(t1);
    if (tid == 0) {
        float g11 = rn1, g22 = rn[i2], g12 = dv[i2];
        float det = fmaf(g11, g22, -g12 * g12);
        float inv = 1.f / det;
        P[2 * n]     = ALPHA * ((g22 * t0 - g12 * t1) * inv);
        P[2 * n + 1] = ALPHA * ((g11 * t1 - g12 * t0) * inv);
        if (n == 0) { idx[0] = i1; idx[1] = i2; }
    }
}

// ---------------- main recurrence ----------------
// 8 waves per batch (block = 512 threads); each wave owns 64 hidden units,
// each lane 1. Rank-2 coupling: waves exchange 2 scalar partials per step
// via a 64 B double-buffered LDS slot.
//
// KEY FIX vs round 3: per-step sync is a RAW s_barrier preceded by
// s_waitcnt lgkmcnt(0) only. __syncthreads() is barrier+fence and the fence
// forces s_waitcnt vmcnt(0) (AMDGPU workgroup-scope release), which drained
// the 12-deep noise prefetch every step -> ~970 cyc/step = HBM latency.
// Raw barrier leaves global loads in flight across the barrier (T4 idiom);
// the compiler still emits counted vmcnt(N) before each buf[] use.
//
// Cross-wave LDS correctness: each wave drains its own ds_write
// (lgkmcnt(0)) before arriving at the barrier; after the barrier all
// partials are visible. Double-buffer ordering: wave w's write(t+2) into
// slot t&1 happens after w passed barrier(t+1), which every wave passes
// only after its read(t). All 512 threads execute identical trip counts,
// so every wave hits every barrier (no divergent-barrier hazard).
__launch_bounds__(512, 1)
__global__ void k_main(const float* __restrict__ u, const float* __restrict__ inoise,
                       const float* __restrict__ rnoise, const float* __restrict__ W_in,
                       const float* __restrict__ W, const float* __restrict__ b_rec,
                       const int* __restrict__ idx, const float* __restrict__ P,
                       float* __restrict__ out) {
    __shared__ __align__(16) float2 lds_x[TT];      // x[t,0:2] = u + ISCALE*input_noise
    __shared__ __align__(16) float2 lds_p[2][WPB];  // per-wave (p0,p1) partials, dbuf
    const int b = blockIdx.x;
    const int tid = threadIdx.x;        // 0..511
    const int wid = tid >> 6;
    const int lane = tid & 63;
    const int i1 = idx[0];
    const int i2 = idx[1];

    // stage x: 1024 floats = 512 float2, one per thread
    {
        const float2* u2 = (const float2*)(u + (size_t)b * TT * 2);
        const float2* n2 = (const float2*)(inoise + (size_t)b * TT * 2);
        float2 a = u2[tid];
        float2 c = n2[tid];
        float2 x;
        x.x = fmaf(ISCALE, c.x, a.x);
        x.y = fmaf(ISCALE, c.y, a.y);
        lds_x[tid] = x;
    }
    __syncthreads();   // once, before the loop: full fence is fine here

    // this lane's hidden unit
    const int n0 = (wid << 6) + lane;   // 0..511
    const float q0 = W[(size_t)i1 * NH + n0];
    const float q1 = W[(size_t)i2 * NH + n0];
    const float A0 = P[2 * n0];
    const float A1 = P[2 * n0 + 1];
    const float w0 = ALPHA * W_in[2 * n0];
    const float w1 = ALPHA * W_in[2 * n0 + 1];
    const float cb = ALPHA * b_rec[n0];
    float s = 0.f;

    const float* nzb = rnoise + (size_t)b * TT * NH + n0;
    float* ob = out + (size_t)b * TT * NH + n0;

    // states[:,0,:] = 0
    __builtin_nontemporal_store(0.f, ob);

    // noise prefetch: PD steps in flight, 4 B/lane each (coalesced 256 B/wave)
    float buf[PD];
#pragma unroll
    for (int k = 0; k < PD; ++k) buf[k] = nzb[(size_t)k * NH];

#define STEP(t_, k_, REFILL_, XX_, XY_)                                              \
    {                                                                                \
        const int t = (t_);                                                          \
        float nz = buf[k_];                                                          \
        if (REFILL_) {                                                               \
            int tp = t + PD; if (tp > NSTEPS) tp = NSTEPS; /* row 511 is valid */    \
            buf[k_] = nzb[(size_t)tp * NH];                                          \
        }                                                                            \
        const float xx = (XX_);                                                      \
        const float xy = (XY_);                                                      \
        float rs = fmaxf(s, 0.f);                                                    \
        float pa = rs * q0;                                                          \
        float pb = rs * q1;                                                          \
        pa = dpp_sum63(pa);                                                          \
        pb = dpp_sum63(pb);                                                          \
        /* base terms are off the p-chain: computed under barrier/LDS latency */     \
        float base = fmaf(ALPHA, nz, cb);                                            \
        base = fmaf(w0, xx, base);                                                   \
        base = fmaf(w1, xy, base);                                                   \
        base = fmaf(OMA, s, base);                                                   \
        if (lane == 63) lds_p[(t) & 1][wid] = make_float2(pa, pb);                   \
        /* drain only LDS (ds_write visibility), NOT vmcnt: prefetch stays live */   \
        asm volatile("s_waitcnt lgkmcnt(0)" ::: "memory");                           \
        __builtin_amdgcn_s_barrier();                                                \
        asm volatile("" ::: "memory");                                               \
        const float4* pp = (const float4*)lds_p[(t) & 1];                            \
        float4 r0 = pp[0];                                                           \
        float4 r1 = pp[1];                                                           \
        float4 r2 = pp[2];                                                           \
        float4 r3 = pp[3];                                                           \
        float p0 = ((r0.x + r0.z) + (r1.x + r1.z)) + ((r2.x + r2.z) + (r3.x + r3.z));\
        float p1 = ((r0.y + r0.w) + (r1.y + r1.w)) + ((r2.y + r2.w) + (r3.y + r3.w));\
        s = fmaf(A1, p1, fmaf(A0, p0, base));                                        \
        __builtin_nontemporal_store(s, ob + (size_t)(t + 1) * NH);                   \
    }

    // 511 = 42*12 + 7: full blocks cover t in [0,504), tail covers [504,511)
    for (int tb = 0; tb < 504; tb += PD) {
        // hoist this block's 12 wave-uniform x reads (6 x ds_read_b128 broadcast)
        const float4* lxs = (const float4*)(lds_x + tb);
        float4 xb[6];
#pragma unroll
        for (int r = 0; r < 6; ++r) xb[r] = lxs[r];
#pragma unroll
        for (int k = 0; k < PD; ++k) {
            STEP(tb + k, k, true,
                 ((k & 1) ? xb[k >> 1].z : xb[k >> 1].x),
                 ((k & 1) ? xb[k >> 1].w : xb[k >> 1].y))
        }
    }
    {
        const float4* lxs = (const float4*)(lds_x + 504);
        float4 xb[4];
#pragma unroll
        for (int r = 0; r < 4; ++r) xb[r] = lxs[r];
#pragma unroll
        for (int k = 0; k < 7; ++k) {
            STEP(504 + k, k, false,
                 ((k & 1) ? xb[k >> 1].z : xb[k >> 1].x),
                 ((k & 1) ? xb[k >> 1].w : xb[k >> 1].y))
        }
    }

#undef STEP
}

// ---------------- launch ----------------

extern "C" void kernel_launch(void* const* d_in, const int* in_sizes, int n_in,
                              void* d_out, int out_size, void* d_ws, size_t ws_size,
                              hipStream_t stream) {
    const float* u      = (const float*)d_in[0];
    const float* inoise = (const float*)d_in[1];
    const float* rnoise = (const float*)d_in[2];
    const float* W_in   = (const float*)d_in[3];
    const float* W      = (const float*)d_in[4];
    const float* b_rec  = (const float*)d_in[5];
    float* out = (float*)d_out;

    char* ws = (char*)d_ws;
    int* idx  = (int*)(ws + 0);
    float* rn = (float*)(ws + 64);
    float* dv = (float*)(ws + 2112);
    float* P  = (float*)(ws + 4160);

    hipLaunchKernelGGL(k_rownorm, dim3(NH), dim3(64), 0, stream, W, rn);
    hipLaunchKernelGGL(k_rowdot, dim3(NH), dim3(64), 0, stream, W, rn, dv);
    hipLaunchKernelGGL(k_computeP, dim3(NH), dim3(64), 0, stream, W, rn, dv, P, idx);
    hipLaunchKernelGGL(k_main, dim3(BATCH), dim3(512), 0, stream,
                       u, inoise, rnoise, W_in, W, b_rec, idx, P, out);
}